// Round 4
// baseline (255.140 us; speedup 1.0000x reference)
//
#include <hip/hip_runtime.h>
#include <stdint.h>

// PennSkipGramModel forward.
// R1/R2: register gathers — compiler serializes, latency-bound, 2.5 TB/s.
// R3: LDS-DMA staging but vmcnt(0) full drain each iter — duty cycle ~45%,
//     still 2.4 TB/s.
// R4: software-pipelined LDS-DMA, depth 2: issue group(i+1) into buffer B
//     BEFORE waiting for group(i) in buffer A, then s_waitcnt vmcnt(7) —
//     oldest 7 drained, next 7 stay in flight during compute. Two DISTINCT
//     __shared__ objects so waitcnt tracking can tell them apart. All
//     per-loop vmem ops are side-effecting global_load_lds builtins (order
//     pinned vs the waitcnt builtin); indices pre-staged to LDS so nothing
//     else touches vmcnt.

#define HV     128                      // floats per row (HALF)
#define BATCH  65536
#define K      5
#define WPB    2                        // waves per block (128 thr)
#define ITERS  16                       // batch elements per wave
#define NBLK   (BATCH / (WPB * ITERS))  // 2048 blocks
#define WBUF   (14 * HV)                // 1792 floats = 7168 B per stage buf
#define NIDX   (3 * 16 + 2 * 16 * K)    // 208 ints per wave

// One instr stages two 512B rows: lane<32 -> rowA, else rowB; HW writes each
// lane's 16B to ldsBase + lane*16 (wave-uniform base + lane*size).
__device__ __forceinline__ void dma_pair(const float* rowA, const float* rowB,
                                         float* ldsBase, int lane) {
    const float* g = ((lane < 32) ? rowA : rowB) + (lane & 31) * 4;
    __builtin_amdgcn_global_load_lds(
        (const __attribute__((address_space(1))) void*)g,
        (__attribute__((address_space(3))) void*)ldsBase,
        16, 0, 0);
}

__device__ __forceinline__ float2 rd2(const float* buf, int off, int lane) {
    return *(const float2*)(buf + off + 2 * lane);
}
__device__ __forceinline__ float dot2(float2 a, float2 b) { return a.x*b.x + a.y*b.y; }
__device__ __forceinline__ float clip10(float x) { return fminf(fmaxf(x, -10.f), 10.f); }

// Issue the 7-DMA group for element `it` of this wave into `buf`.
// Row offsets (floats): ul@0 ur@128 vl@256 vr@384 nl[k]@512+128k nr[k]@1152+128k
__device__ __forceinline__ void issue_group(
    const float* u_l, const float* u_r, const float* v_l, const float* v_r,
    const int* ix, int it, float* buf, int lane)
{
    const int iu  = ix[it];
    const int ivl = ix[16 + it];
    const int ivr = ix[32 + it];
    const int o   = 48  + it * K;   // nl block
    const int p   = 128 + it * K;   // nr block
    dma_pair(u_l + (size_t)iu       * HV, u_r + (size_t)iu       * HV, buf + 0*256, lane);
    dma_pair(v_l + (size_t)ivl      * HV, v_r + (size_t)ivr      * HV, buf + 1*256, lane);
    dma_pair(v_l + (size_t)ix[o+0]  * HV, v_l + (size_t)ix[o+1]  * HV, buf + 2*256, lane);
    dma_pair(v_l + (size_t)ix[o+2]  * HV, v_l + (size_t)ix[o+3]  * HV, buf + 3*256, lane);
    dma_pair(v_l + (size_t)ix[o+4]  * HV, v_r + (size_t)ix[p+0]  * HV, buf + 4*256, lane);
    dma_pair(v_r + (size_t)ix[p+1]  * HV, v_r + (size_t)ix[p+2]  * HV, buf + 5*256, lane);
    dma_pair(v_r + (size_t)ix[p+3]  * HV, v_r + (size_t)ix[p+4]  * HV, buf + 6*256, lane);
}

// Consume one staged element: 12 dots, 64-lane butterflies, -logsigmoid sum.
__device__ __forceinline__ float consume(const float* buf, int lane) {
    float2 ul = rd2(buf, 0,   lane);
    float2 ur = rd2(buf, 128, lane);
    float s[12];
    s[0] = dot2(ul, rd2(buf, 256, lane));
    s[1] = dot2(ur, rd2(buf, 384, lane));
    #pragma unroll
    for (int k = 0; k < K; ++k) {
        s[2 + k] = dot2(ul, rd2(buf,  512 + 128*k, lane));
        s[7 + k] = dot2(ur, rd2(buf, 1152 + 128*k, lane));
    }
    #pragma unroll
    for (int m = 1; m < 64; m <<= 1) {
        #pragma unroll
        for (int j = 0; j < 12; ++j) s[j] += __shfl_xor(s[j], m, 64);
    }
    float a = __logf(1.f + __expf(-clip10(s[0])))    // -logsig(pos_l)
            + __logf(1.f + __expf(-clip10(s[1])));   // -logsig(pos_r)
    #pragma unroll
    for (int j = 2; j < 12; ++j)
        a += __logf(1.f + __expf(clip10(s[j])));     // -logsig(-neg)
    return a;
}

__global__ __launch_bounds__(128) void skipgram_fwd(
    const float* __restrict__ u_l, const float* __restrict__ u_r,
    const float* __restrict__ v_l, const float* __restrict__ v_r,
    const int* __restrict__ pos_u, const int* __restrict__ pos_vl,
    const int* __restrict__ pos_vr, const int* __restrict__ neg_vl,
    const int* __restrict__ neg_vr, float* __restrict__ out)
{
    __shared__ float bufA[WPB][WBUF];   // distinct objects: lets the waitcnt
    __shared__ float bufB[WPB][WBUF];   // tracker tell the two stages apart
    __shared__ int   idx[WPB][NIDX];
    __shared__ float wsum[WPB];

    const int tid  = threadIdx.x;
    const int lane = tid & 63;
    const int wv   = tid >> 6;
    const int b0   = (blockIdx.x * WPB + wv) * ITERS;

    // ---- stage this wave's 208 indices into LDS (one-time; keeps the main
    //      loop's vmcnt traffic == our DMA groups only) ----
    for (int i = lane; i < NIDX; i += 64) {
        int v;
        if      (i < 16)  v = pos_u [b0 + i];
        else if (i < 32)  v = pos_vl[b0 + i - 16];
        else if (i < 48)  v = pos_vr[b0 + i - 32];
        else if (i < 128) v = neg_vl[b0 * K + i - 48];
        else              v = neg_vr[b0 * K + i - 128];
        idx[wv][i] = v;
    }
    __builtin_amdgcn_s_waitcnt(0x0070);   // lgkmcnt(0): idx writes visible
    // (vmcnt drains naturally: ds_write depends on the loaded values)

    const int* ix = idx[wv];
    float* bA = &bufA[wv][0];
    float* bB = &bufB[wv][0];
    float acc = 0.0f;

    // ---- pipelined main loop, depth 2, never a full vmcnt drain ----
    issue_group(u_l, u_r, v_l, v_r, ix, 0, bA, lane);          // out: 7
    for (int it = 0; it + 2 < ITERS; it += 2) {
        issue_group(u_l, u_r, v_l, v_r, ix, it + 1, bB, lane); // out: 14
        __builtin_amdgcn_s_waitcnt(0x0F77);    // vmcnt(7): group(it)@A landed
        __builtin_amdgcn_sched_barrier(0);
        acc += consume(bA, lane);
        issue_group(u_l, u_r, v_l, v_r, ix, it + 2, bA, lane); // out: 14
        __builtin_amdgcn_s_waitcnt(0x0F77);    // vmcnt(7): group(it+1)@B landed
        __builtin_amdgcn_sched_barrier(0);
        acc += consume(bB, lane);
    }
    // final pair (it = ITERS-2, ITERS-1): no further issue, drain fully
    issue_group(u_l, u_r, v_l, v_r, ix, ITERS - 1, bB, lane);  // out: 14
    __builtin_amdgcn_s_waitcnt(0x0F77);        // group(ITERS-2)@A landed
    __builtin_amdgcn_sched_barrier(0);
    acc += consume(bA, lane);
    __builtin_amdgcn_s_waitcnt(0x0F70);        // vmcnt(0): last group@B landed
    __builtin_amdgcn_sched_barrier(0);
    acc += consume(bB, lane);

    if (lane == 0) wsum[wv] = acc;
    __syncthreads();
    if (tid == 0) {
        float s = wsum[0] + wsum[1];
        atomicAdd(out, s * (1.0f / BATCH));
    }
}

extern "C" void kernel_launch(void* const* d_in, const int* in_sizes, int n_in,
                              void* d_out, int out_size, void* d_ws, size_t ws_size,
                              hipStream_t stream) {
    const float* u_l   = (const float*)d_in[0];
    const float* u_r   = (const float*)d_in[1];
    const float* v_l   = (const float*)d_in[2];
    const float* v_r   = (const float*)d_in[3];
    const int* pos_u   = (const int*)d_in[4];
    const int* pos_vl  = (const int*)d_in[5];
    const int* pos_vr  = (const int*)d_in[6];
    const int* neg_vl  = (const int*)d_in[7];
    const int* neg_vr  = (const int*)d_in[8];
    float* out = (float*)d_out;

    hipMemsetAsync(out, 0, sizeof(float), stream);

    skipgram_fwd<<<NBLK, 128, 0, stream>>>(
        u_l, u_r, v_l, v_r, pos_u, pos_vl, pos_vr, neg_vl, neg_vr, out);
}

// Round 5
// 233.965 us; speedup vs baseline: 1.0905x; 1.0905x over previous
//
#include <hip/hip_runtime.h>

// PennSkipGramModel forward: mean over B of
//   -logsig(clip(u_l·v_l)) + -logsig(clip(u_r·v_r))
//   + sum_k -logsig(-clip(u_l·neg_l[k])) + sum_k -logsig(-clip(u_r·neg_r[k]))
//
// FINAL (revert to R1/R2 structure — best measured: 90.2 us kernel, 2.59 TB/s).
// Session evidence: this problem is a 512B-granule random gather (14 rows /
// batch element, 228 MB fabric fetch after L2/L3 dedup vs 149.6 MB distinct
// floor). Four structures (register gather, LDS-DMA full-drain, LDS-DMA
// pipelined vmcnt(7)) all converge at 2.4-2.6 TB/s with implied loaded
// latency ~9000 cyc (10x unloaded) -> queue-saturated memory system, i.e.
// the random-gather throughput ceiling, NOT a latency/occupancy problem.
// The simplest structure wins: 16 lanes per batch element, float4 loads
// (coalesced 256B bursts), u fragments reused in-register across 12 dots,
// 4-step shfl butterfly, one atomic per block.

#define HV4   32        // float4s per 128-float row
#define BATCH 65536
#define K     5

__device__ __forceinline__ float dot4(float4 a, float4 b) {
    return a.x * b.x + a.y * b.y + a.z * b.z + a.w * b.w;
}

__device__ __forceinline__ float red16(float v) {
    v += __shfl_xor(v, 8, 16);
    v += __shfl_xor(v, 4, 16);
    v += __shfl_xor(v, 2, 16);
    v += __shfl_xor(v, 1, 16);
    return v;   // full sum in all 16 lanes
}

__device__ __forceinline__ float clip10(float x) {
    return fminf(fmaxf(x, -10.0f), 10.0f);
}

__global__ __launch_bounds__(256) void skipgram_fwd(
    const float* __restrict__ u_l, const float* __restrict__ u_r,
    const float* __restrict__ v_l, const float* __restrict__ v_r,
    const int* __restrict__ pos_u, const int* __restrict__ pos_vl,
    const int* __restrict__ pos_vr, const int* __restrict__ neg_vl,
    const int* __restrict__ neg_vr, float* __restrict__ out)
{
    const int tid  = threadIdx.x;
    const int lane = tid & 15;      // lane within 16-lane group
    const int grp  = tid >> 4;      // 0..15 groups per block
    const int b    = (blockIdx.x << 4) + grp;

    const int iu  = pos_u[b];
    const int ivl = pos_vl[b];
    const int ivr = pos_vr[b];

    // u fragments: loaded once, reused for all 12 dots
    const float4* ULr = (const float4*)u_l + (size_t)iu * HV4;
    const float4* URr = (const float4*)u_r + (size_t)iu * HV4;
    float4 ul0 = ULr[lane], ul1 = ULr[lane + 16];
    float4 ur0 = URr[lane], ur1 = URr[lane + 16];

    const float4* VLr = (const float4*)v_l + (size_t)ivl * HV4;
    const float4* VRr = (const float4*)v_r + (size_t)ivr * HV4;
    float4 vl0 = VLr[lane], vl1 = VLr[lane + 16];
    float4 vr0 = VRr[lane], vr1 = VRr[lane + 16];

    float sl = red16(dot4(ul0, vl0) + dot4(ul1, vl1));
    float sr = red16(dot4(ur0, vr0) + dot4(ur1, vr1));

    // -log_sigmoid(x) = log(1 + exp(-x)),  x already clipped to [-10,10]
    float acc = __logf(1.0f + __expf(-clip10(sl)))
              + __logf(1.0f + __expf(-clip10(sr)));

    #pragma unroll
    for (int k = 0; k < K; ++k) {
        const int inl = neg_vl[b * K + k];
        const int inr = neg_vr[b * K + k];
        const float4* NL = (const float4*)v_l + (size_t)inl * HV4;
        const float4* NR = (const float4*)v_r + (size_t)inr * HV4;
        float4 nl0 = NL[lane], nl1 = NL[lane + 16];
        float4 nr0 = NR[lane], nr1 = NR[lane + 16];
        float snl = red16(dot4(ul0, nl0) + dot4(ul1, nl1));
        float snr = red16(dot4(ur0, nr0) + dot4(ur1, nr1));
        // -log_sigmoid(-x) = log(1 + exp(x))
        acc += __logf(1.0f + __expf(clip10(snl)))
             + __logf(1.0f + __expf(clip10(snr)));
    }

    // block reduction: one value per 16-lane group -> one atomic per block
    __shared__ float smem[16];
    if (lane == 0) smem[grp] = acc;
    __syncthreads();
    if (tid == 0) {
        float s = 0.0f;
        #pragma unroll
        for (int i = 0; i < 16; ++i) s += smem[i];
        atomicAdd(out, s * (1.0f / BATCH));
    }
}

extern "C" void kernel_launch(void* const* d_in, const int* in_sizes, int n_in,
                              void* d_out, int out_size, void* d_ws, size_t ws_size,
                              hipStream_t stream) {
    const float* u_l   = (const float*)d_in[0];
    const float* u_r   = (const float*)d_in[1];
    const float* v_l   = (const float*)d_in[2];
    const float* v_r   = (const float*)d_in[3];
    const int* pos_u   = (const int*)d_in[4];
    const int* pos_vl  = (const int*)d_in[5];
    const int* pos_vr  = (const int*)d_in[6];
    const int* neg_vl  = (const int*)d_in[7];
    const int* neg_vr  = (const int*)d_in[8];
    float* out = (float*)d_out;

    // d_out is poisoned (0xAA) before every timed launch — zero it on-stream.
    hipMemsetAsync(out, 0, sizeof(float), stream);

    skipgram_fwd<<<BATCH / 16, 256, 0, stream>>>(
        u_l, u_r, v_l, v_r, pos_u, pos_vl, pos_vr, neg_vl, neg_vr, out);
}